// Round 1
// baseline (349.678 us; speedup 1.0000x reference)
//
#include <hip/hip_runtime.h>

#define BATCH 64
#define NN 256
#define GAMMA_F 0.01f
#define INVG_F 100.0f
#define BIG_F 1e8f

// One block per batch element. Thread tid owns DP row i = tid+1 (1..256).
// Forward: anti-diagonal wavefront k = i+j, 3 rolling LDS diagonal buffers,
// V stored to global workspace for the backward pass.
// Backward: reverse wavefront computing the soft-alignment E on the fly,
// accumulating sum(E * (i-j)^2) per batch; V diagonals prefetched from global
// one step ahead into 4 rolling LDS buffers (4, not 3, so a single barrier per
// step suffices without a WAR race on the buffer being recycled).
__global__ __launch_bounds__(256) void dilate_dp_kernel(
    const float* __restrict__ y_pred,
    const float* __restrict__ y_true,
    float* __restrict__ Rg,   // [BATCH, NN, NN] forward DP values V[i,j], i,j in 1..N
    float* __restrict__ sd,   // [BATCH] soft-DTW values
    float* __restrict__ ts)   // [BATCH] sum(E * omega)
{
    const int b = blockIdx.x;
    const int tid = threadIdx.x;
    const int i = tid + 1;               // DP row index, 1..256

    __shared__ float t_s[NN], o_s[NN];
    __shared__ float dbuf[3][NN + 1];    // forward V diagonals, indexed by row i (0..256)
    __shared__ float ebuf[3][NN + 2];    // backward E diagonals
    __shared__ float rbuf[4][NN + 2];    // backward V diagonals (reloaded)
    __shared__ float red[256];

    t_s[tid] = y_true[b * NN + tid];
    o_s[tid] = y_pred[b * NN + tid];

    if (tid == 0) {
        dbuf[0][0] = 0.0f;   // V[0,0]
        dbuf[1][0] = BIG_F;  // V[0,1]
        dbuf[1][1] = BIG_F;  // V[1,0]
    }
    __syncthreads();

    float* __restrict__ Rb = Rg + (size_t)b * (NN * NN);
    const float ti = t_s[i - 1];         // own row's t value (own LDS write, no race)

    // ---------------- forward ----------------
    int p0 = 0, p1 = 1, p2 = 2;          // diag k-2, k-1, k
    float myv = 0.0f;
    for (int k = 2; k <= 2 * NN; ++k) {
        const int j = k - i;
        float* d0 = dbuf[p0];
        float* d1 = dbuf[p1];
        float* d2 = dbuf[p2];
        if (j >= 1 && j <= NN) {
            float left = d1[i];          // V[i, j-1]
            float up   = d1[i - 1];      // V[i-1, j]
            float dg   = d0[i - 1];      // V[i-1, j-1]
            float dd = ti - o_s[j - 1];
            dd *= dd;                    // D[i,j]
            float m = fminf(fminf(left, dg), up);
            float s = __expf((m - left) * INVG_F)
                    + __expf((m - dg) * INVG_F)
                    + __expf((m - up) * INVG_F);
            float v = dd + m - GAMMA_F * __logf(s);
            d2[i] = v;
            Rb[(i - 1) * NN + (j - 1)] = v;
            myv = v;
        }
        if (k <= NN) {                   // borders of diagonal k
            if (tid == 0) d2[0] = BIG_F; // V[0,k]
            if (tid == 1) d2[k] = BIG_F; // V[k,0] (row k never computed, no clash)
        }
        __syncthreads();
        int t0 = p0; p0 = p1; p1 = p2; p2 = t0;
    }
    if (i == NN) sd[b] = myv;            // V[N,N], last value computed by row N

    // ---------------- backward ----------------
    // E[i,j] = a*E[i+1,j] + b*E[i,j+1] + c*E[i+1,j+1]; seed E[N,N]=1.
    // All guarded LDS reads provably hit cells written on the corresponding
    // diagonal, so no zero-init of ebuf/rbuf is required.
    float pf = 0.0f;                     // prefetched V[i, k-i] for current k
    if (i == NN) pf = Rb[(NN - 1) * NN + (NN - 1)];
    int q0 = 0, q1 = 1, q2 = 2, q3 = 3;  // diag k, k+1, k+2, (recycle)
    int e0i = 0, e1i = 1, e2i = 2;       // diag k, k+1, k+2
    float acc = 0.0f;
    for (int k = 2 * NN; k >= 2; --k) {
        const int j = k - i;
        const bool valid = (j >= 1 && j <= NN);
        float* rc = rbuf[q0];
        if (valid) rc[i] = pf;           // publish V diag k
        // prefetch diag k-1 for next iteration (latency hidden by barrier+compute)
        float pfn = 0.0f;
        const int jn = k - 1 - i;
        if (jn >= 1 && jn <= NN) pfn = Rb[(i - 1) * NN + (jn - 1)];
        __syncthreads();
        float* rk  = rbuf[q0];
        float* rk1 = rbuf[q1];
        float* rk2 = rbuf[q2];
        float* e0 = ebuf[e0i];
        float* e1 = ebuf[e1i];
        float* e2 = ebuf[e2i];
        if (valid) {
            float E;
            if (k == 2 * NN) {
                E = 1.0f;                // seed at (N,N)
            } else {
                float rij = rk[i];
                float oj = o_s[j - 1];
                float E3 = 0.0f;
                if (i < NN) {            // successor (i+1, j)
                    float d = t_s[i] - oj; d *= d;
                    E3 += __expf((rk1[i + 1] - rij - d) * INVG_F) * e1[i + 1];
                }
                if (j < NN) {            // successor (i, j+1)
                    float d = ti - o_s[j]; d *= d;
                    E3 += __expf((rk1[i] - rij - d) * INVG_F) * e1[i];
                }
                if (i < NN && j < NN) {  // successor (i+1, j+1)
                    float d = t_s[i] - o_s[j]; d *= d;
                    E3 += __expf((rk2[i + 1] - rij - d) * INVG_F) * e2[i + 1];
                }
                E = E3;
            }
            e0[i] = E;
            float dij = (float)(i - j);
            acc += E * dij * dij;
        }
        pf = pfn;
        int tq = q3; q3 = q2; q2 = q1; q1 = q0; q0 = tq;
        int te = e2i; e2i = e1i; e1i = e0i; e0i = te;
    }

    // block reduction of acc -> ts[b]
    red[tid] = acc;
    __syncthreads();
    for (int s = 128; s > 0; s >>= 1) {
        if (tid < s) red[tid] += red[tid + s];
        __syncthreads();
    }
    if (tid == 0) ts[b] = red[0];
}

// loss = 0.5 * mean_b(sd) + 0.5 * mean_b(ts) / N^2, reduced by one wave.
__global__ void dilate_finalize(const float* __restrict__ sd,
                                const float* __restrict__ ts,
                                float* __restrict__ out)
{
    int t = threadIdx.x;
    float v = 0.5f * (sd[t] * (1.0f / BATCH)
                    + ts[t] * (1.0f / ((float)BATCH * (float)(NN * NN))));
    for (int o = 32; o > 0; o >>= 1) v += __shfl_down(v, o);
    if (t == 0) out[0] = v;
}

extern "C" void kernel_launch(void* const* d_in, const int* in_sizes, int n_in,
                              void* d_out, int out_size, void* d_ws, size_t ws_size,
                              hipStream_t stream)
{
    const float* y_pred = (const float*)d_in[0];   // [64,256,1]
    const float* y_true = (const float*)d_in[1];   // [64,256,1]
    float* Rg = (float*)d_ws;                      // 64*256*256 f32 = 16 MiB
    float* sd = Rg + (size_t)BATCH * NN * NN;
    float* ts = sd + BATCH;
    dilate_dp_kernel<<<BATCH, 256, 0, stream>>>(y_pred, y_true, Rg, sd, ts);
    dilate_finalize<<<1, 64, 0, stream>>>(sd, ts, (float*)d_out);
}

// Round 2
// 272.145 us; speedup vs baseline: 1.2849x; 1.2849x over previous
//
#include <hip/hip_runtime.h>

#define BATCH 64
#define NN 256
#define GAMMA_F 0.01f
#define INVG_F 100.0f
#define BIG_F 1e8f
#define PAD 256

// One wave (64 lanes) per batch. Lane owns 4 consecutive DP rows
// (i = 4*lane+1 .. 4*lane+4) in registers. Anti-diagonal wavefront k = i+j,
// k = 2..512. Register state per lane:
//   A[r]  = V[i_r, (k-1)-i_r]   (previous diagonal)
//   Bv[r] = V[i_r, (k-2)-i_r]   (diagonal before that)
//   At/Bt = forward-mode tangents of the same cells, seed omega[i,j]=(i-j)^2
// Cross-lane row boundary via __shfl_up (wave-synchronous, no barriers).
// Temporal term = tangent of V[N,N] (JVP) -> no backward pass, no V storage.
template <bool P1>
__device__ __forceinline__ void dp_step(
    int k, int lane, const float* __restrict__ op, const float T[4],
    float A[4], float Bv[4], float At[4], float Bt[4], float dif0)
{
    // neighbor-row values from lane-1 (row 4*lane): needed by r==0 cells
    float sA  = __shfl_up(A[3], 1);
    float sB  = __shfl_up(Bv[3], 1);
    float sAt = __shfl_up(At[3], 1);
    float sBt = __shfl_up(Bt[3], 1);

    float nv[4], nvt[4];
    bool  val[4];

    #pragma unroll
    for (int r = 0; r < 4; ++r) {
        const int i = 4 * lane + 1 + r;
        const int j = k - i;

        float o = op[3 - r];                 // o_pad[PAD + j - 1], in-bounds by padding

        float left = A[r],                 lt = At[r];
        float up   = r ? A[r - 1]  : sA,   ut = r ? At[r - 1] : sAt;
        float dg   = r ? Bv[r - 1] : sB,   dt = r ? Bt[r - 1] : sBt;

        if (P1) {                            // k <= 257: j==1 and i==1 boundaries live
            const bool j1 = (j == 1);
            left = j1 ? BIG_F : left;  lt = j1 ? 0.0f : lt;
            dg   = j1 ? BIG_F : dg;    dt = j1 ? 0.0f : dt;
            if (r == 0) {                    // i==1 possible only for lane 0, r 0
                const bool i1 = (lane == 0);
                up = i1 ? BIG_F : up;  ut = i1 ? 0.0f : ut;
                dg = i1 ? (j1 ? 0.0f : BIG_F) : dg;
                dt = i1 ? 0.0f : dt;
            }
        }

        float dd = T[r] - o; dd *= dd;       // D[i,j]

        float m  = fminf(fminf(left, dg), up);
        float el = __expf((m - left) * INVG_F);
        float ed = __expf((m - dg)   * INVG_F);
        float eu = __expf((m - up)   * INVG_F);
        float s  = el + ed + eu;
        float v  = dd + m - GAMMA_F * __logf(s);

        // tangent: vt = omega + (el*lt + ed*dt + eu*ut)/s
        float rs  = __builtin_amdgcn_rcpf(s);
        float num = fmaf(el, lt, fmaf(ed, dt, eu * ut));
        float dif = dif0 + 2.0f * (float)r;  // (i - j) as float
        float vt  = fmaf(num, rs, dif * dif);

        nv[r] = v; nvt[r] = vt;
        val[r] = P1 ? (j >= 1) : (j <= NN);
    }

    #pragma unroll
    for (int r = 0; r < 4; ++r) {
        Bv[r] = A[r]; Bt[r] = At[r];
        if (val[r]) { A[r] = nv[r]; At[r] = nvt[r]; }
    }
}

__global__ __launch_bounds__(64) void dilate_fwd_jvp(
    const float* __restrict__ y_pred,
    const float* __restrict__ y_true,
    float* __restrict__ sd,   // [BATCH] soft-DTW values V[N,N]
    float* __restrict__ ts)   // [BATCH] tangent = sum(E * omega)
{
    const int b = blockIdx.x;
    const int lane = threadIdx.x;

    __shared__ float o_pad[NN + 2 * PAD];    // padded so o reads never need clamping

    const float4 zero4 = make_float4(0.f, 0.f, 0.f, 0.f);
    ((float4*)o_pad)[lane] = zero4;                        // left pad
    ((float4*)(o_pad + PAD + NN))[lane] = zero4;           // right pad
    ((float4*)(o_pad + PAD))[lane] = ((const float4*)(y_pred + b * NN))[lane];

    const float4 tv = ((const float4*)(y_true + b * NN))[lane];
    float T[4] = {tv.x, tv.y, tv.z, tv.w};

    __syncthreads();                          // single wave; orders LDS writes/reads

    float A[4], Bv[4], At[4], Bt[4];
    #pragma unroll
    for (int r = 0; r < 4; ++r) { A[r] = BIG_F; Bv[r] = BIG_F; At[r] = 0.f; Bt[r] = 0.f; }

    // op[3-r] = o_pad[PAD + (k - i_r - 1)]; advance by one float per k
    const float* op = o_pad + PAD - 4 * lane - 3;
    float dif0 = (float)(8 * lane);           // 2*i_0 - k at k=2

    #pragma unroll 2
    for (int k = 2; k <= 257; ++k) {          // phase 1: boundary selects active
        dp_step<true>(k, lane, op, T, A, Bv, At, Bt, dif0);
        ++op; dif0 -= 1.0f;
    }
    #pragma unroll 2
    for (int k = 258; k <= 512; ++k) {        // phase 2: no boundaries can occur
        dp_step<false>(k, lane, op, T, A, Bv, At, Bt, dif0);
        ++op; dif0 -= 1.0f;
    }

    if (lane == 63) {                         // cell (256,256) lives in r=3 of lane 63
        sd[b] = A[3];
        ts[b] = At[3];
    }
}

// loss = 0.5 * mean_b(sd) + 0.5 * mean_b(ts) / N^2, reduced by one wave.
__global__ void dilate_finalize(const float* __restrict__ sd,
                                const float* __restrict__ ts,
                                float* __restrict__ out)
{
    int t = threadIdx.x;
    float v = 0.5f * (sd[t] * (1.0f / BATCH)
                    + ts[t] * (1.0f / ((float)BATCH * (float)(NN * NN))));
    for (int o = 32; o > 0; o >>= 1) v += __shfl_down(v, o);
    if (t == 0) out[0] = v;
}

extern "C" void kernel_launch(void* const* d_in, const int* in_sizes, int n_in,
                              void* d_out, int out_size, void* d_ws, size_t ws_size,
                              hipStream_t stream)
{
    const float* y_pred = (const float*)d_in[0];   // [64,256,1]
    const float* y_true = (const float*)d_in[1];   // [64,256,1]
    float* sd = (float*)d_ws;
    float* ts = sd + BATCH;
    dilate_fwd_jvp<<<BATCH, 64, 0, stream>>>(y_pred, y_true, sd, ts);
    dilate_finalize<<<1, 64, 0, stream>>>(sd, ts, (float*)d_out);
}

// Round 3
// 172.388 us; speedup vs baseline: 2.0284x; 1.5787x over previous
//
#include <hip/hip_runtime.h>

#define BATCH 64
#define NN 256
#define PAD 256
// Scaled DP domain: V' = V * CSC, CSC = (1/gamma)*log2(e), gamma = 0.01.
// Softmin weights become raw exp2 of differences; v' = CSC*dd + m' - log2(s).
#define CSC   144.26950408889634f
#define RCSC  0.0069314718055994531f   // 1/CSC = gamma*ln(2)
#define BIGS  1.4426950408889634e10f   // 1e8 * CSC (scaled boundary)

// One wave per batch; lane owns rows i = 4*lane+1 .. 4*lane+4.
// A* = V' on diagonal k-1, B* = V' on diagonal k-2 (per owned row);
// U*/W* = forward-mode tangents of the same cells (seed omega[i,j]=(i-j)^2).
// psA/psU = last step's shfl result (neighbor row's diag k-2) -> 2 shfls/step.
// Temporal term = tangent of V[N,N] (JVP identity) -> single forward pass.

#define CELL(NV, NT, L, DG, UP, LT, DT, UT, TT, OO, DR) {            \
    float m  = fminf(fminf((L), (DG)), (UP));                        \
    float el = __builtin_amdgcn_exp2f(m - (L));                      \
    float ed = __builtin_amdgcn_exp2f(m - (DG));                     \
    float eu = __builtin_amdgcn_exp2f(m - (UP));                     \
    float s  = el + ed + eu;                                         \
    float x  = (TT) - (OO);                                          \
    NV = fmaf(CSC * x, x, m - __builtin_amdgcn_logf(s));             \
    float num = fmaf(el, (LT), fmaf(ed, (DT), eu * (UT)));           \
    float dr  = (DR);                                                \
    NT = fmaf(num, __builtin_amdgcn_rcpf(s), dr * dr);               \
}

#define DSTEP(NW) {                                                  \
    float sA = __shfl_up(A3, 1);                                     \
    float sU = __shfl_up(U3, 1);                                     \
    sA = (lane == 0) ? BIGS : sA;                                    \
    sU = (lane == 0) ? 0.f  : sU;                                    \
    w3 = w2; w2 = w1; w1 = w0; w0 = (NW);                            \
    float n0, n1, n2, n3, q0, q1, q2, q3;                            \
    CELL(n0, q0, A0, psA, sA, U0, psU, sU, T0, w0, df)               \
    CELL(n1, q1, A1, B0,  A0, U1, W0,  U0, T1, w1, df + 2.f)         \
    CELL(n2, q2, A2, B1,  A1, U2, W1,  U1, T2, w2, df + 4.f)         \
    CELL(n3, q3, A3, B2,  A2, U3, W2,  U2, T3, w3, df + 6.f)         \
    psA = sA; psU = sU;                                              \
    B0 = A0; B1 = A1; B2 = A2; B3 = A3;                              \
    W0 = U0; W1 = U1; W2 = U2; W3 = U3;                              \
    A0 = ((unsigned)(c0    ) < 256u) ? n0 : A0;                      \
    U0 = ((unsigned)(c0    ) < 256u) ? q0 : U0;                      \
    A1 = ((unsigned)(c0 - 1) < 256u) ? n1 : A1;                      \
    U1 = ((unsigned)(c0 - 1) < 256u) ? q1 : U1;                      \
    A2 = ((unsigned)(c0 - 2) < 256u) ? n2 : A2;                      \
    U2 = ((unsigned)(c0 - 2) < 256u) ? q2 : U2;                      \
    A3 = ((unsigned)(c0 - 3) < 256u) ? n3 : A3;                      \
    U3 = ((unsigned)(c0 - 3) < 256u) ? q3 : U3;                      \
    df -= 1.f; c0 += 1;                                              \
}

__global__ __launch_bounds__(64) void dilate_fused(
    const float* __restrict__ y_pred,
    const float* __restrict__ y_true,
    float* __restrict__ out)
{
    const int b = blockIdx.x;
    const int lane = threadIdx.x;

    __shared__ float o_pad[1024];            // [0,256): zeros | [256,512): o | rest zeros
    const float4 z4 = make_float4(0.f, 0.f, 0.f, 0.f);
    ((float4*)o_pad)[lane]       = z4;
    ((float4*)o_pad)[lane + 128] = z4;
    ((float4*)o_pad)[lane + 192] = z4;
    ((float4*)o_pad)[lane + 64]  = ((const float4*)(y_pred + b * NN))[lane];
    const float4 tv = ((const float4*)(y_true + b * NN))[lane];
    __syncthreads();

    const float T0 = tv.x, T1 = tv.y, T2 = tv.z, T3 = tv.w;

    float A0 = BIGS, A1 = BIGS, A2 = BIGS, A3 = BIGS;
    float B0 = BIGS, B1 = BIGS, B2 = BIGS, B3 = BIGS;
    float U0 = 0.f, U1 = 0.f, U2 = 0.f, U3 = 0.f;
    float W0 = 0.f, W1 = 0.f, W2 = 0.f, W3 = 0.f;
    float psA = (lane == 0) ? 0.f : BIGS;    // V[0,0] = 0 corner seed
    float psU = 0.f;
    float w0 = 0.f, w1 = 0.f, w2 = 0.f, w3 = 0.f;

    float df = (float)(8 * lane);            // (i_0 - j_0) at k = 2
    int   c0 = -4 * lane;                    // k - 4*lane - 2 at k = 2

    // o window refill: step k, r=0 needs o[k - 4*lane - 2] (0-based)
    const float* oin = o_pad + (PAD - 2 - 4 * lane);
    float4 nxt = *(const float4*)(oin + 2);  // chunk k = 2..5
    oin += 6;

    for (int kb = 2; kb < 514; kb += 4) {    // k = 2..513 (513 masked off)
        const float4 cur = nxt;
        nxt = *(const float4*)oin;           // prefetch chunk kb+4
        oin += 4;
        DSTEP(cur.x)
        DSTEP(cur.y)
        DSTEP(cur.z)
        DSTEP(cur.w)
    }

    if (lane == 63) {                        // cell (256,256): r=3 of lane 63
        float loss = 0.5f * (A3 * RCSC) * (1.0f / BATCH)
                   + 0.5f * U3 * (1.0f / ((float)BATCH * (float)(NN * NN)));
        atomicAdd(out, loss);
    }
}

extern "C" void kernel_launch(void* const* d_in, const int* in_sizes, int n_in,
                              void* d_out, int out_size, void* d_ws, size_t ws_size,
                              hipStream_t stream)
{
    const float* y_pred = (const float*)d_in[0];   // [64,256,1] -> o (columns)
    const float* y_true = (const float*)d_in[1];   // [64,256,1] -> t (rows)
    hipMemsetAsync(d_out, 0, sizeof(float), stream);
    dilate_fused<<<BATCH, 64, 0, stream>>>(y_pred, y_true, (float*)d_out);
}

// Round 4
// 148.016 us; speedup vs baseline: 2.3624x; 1.1647x over previous
//
#include <hip/hip_runtime.h>

#define BATCH 64
#define NN 256
#define PAD 256
// Scaled DP domain: V' = V * CSC, CSC = (1/gamma)*log2(e), gamma = 0.01.
// Softmin weights are raw exp2 of differences; v' = CSC*dd + m' - log2(s).
#define CSC   144.26950408889634f
#define RCSC  0.0069314718055994531f   // 1/CSC = gamma*ln(2)
#define BIGS  1.4426950408889634e10f   // 1e8 * CSC (scaled boundary)

// One wave per batch; lane owns rows i = 4*lane+1 .. 4*lane+4.
// A* = V' on diag k-1, B* = V' on diag k-2; U*/W* = JVP tangents of same
// (seed omega[i,j]=(i-j)^2). Temporal term = tangent of V[N,N].
// No validity masks: BIGS self-propagates through pre-start cells (drift
// <=~1e6 on 1.44e10, ulp 1024 -> still acts as +inf under exp2), and garbage
// tangents are annihilated by exp2(-1e10)=0 weights at first real contact.
// Lane-neighbor row handoff via DPP wave_shr1 (VALU, no LDS round-trip);
// invalid lane 0 gets BIGS / 0 via the update_dpp old-operand for free.

__device__ __forceinline__ float shr1_big(float x, float big) {
    return __int_as_float(__builtin_amdgcn_update_dpp(
        __float_as_int(big), __float_as_int(x), 0x138, 0xF, 0xF, false));
}
__device__ __forceinline__ float shr1_zero(float x) {
    return __int_as_float(__builtin_amdgcn_update_dpp(
        0, __float_as_int(x), 0x138, 0xF, 0xF, true));
}

#define CELL(NV, NT, L, DG, UP, LT, DT, UT, TT, OO, DR) {            \
    float m  = fminf(fminf((L), (DG)), (UP));                        \
    float el = __builtin_amdgcn_exp2f(m - (L));                      \
    float ed = __builtin_amdgcn_exp2f(m - (DG));                     \
    float eu = __builtin_amdgcn_exp2f(m - (UP));                     \
    float s  = el + ed + eu;                                         \
    float x  = (TT) - (OO);                                          \
    NV = fmaf(CSC * x, x, m - __builtin_amdgcn_logf(s));             \
    float num = fmaf(el, (LT), fmaf(ed, (DT), eu * (UT)));           \
    float dr  = (DR);                                                \
    NT = fmaf(num, __builtin_amdgcn_rcpf(s), dr * dr);               \
}

#define DSTEP(NW) {                                                  \
    float sA = shr1_big(A3, bigs);                                   \
    float sU = shr1_zero(U3);                                        \
    w3 = w2; w2 = w1; w1 = w0; w0 = (NW);                            \
    float n0, n1, n2, n3, q0, q1, q2, q3;                            \
    CELL(n0, q0, A0, psA, sA, U0, psU, sU, T0, w0, df)               \
    CELL(n1, q1, A1, B0,  A0, U1, W0,  U0, T1, w1, df + 2.f)         \
    CELL(n2, q2, A2, B1,  A1, U2, W1,  U1, T2, w2, df + 4.f)         \
    CELL(n3, q3, A3, B2,  A2, U3, W2,  U2, T3, w3, df + 6.f)         \
    psA = sA; psU = sU;                                              \
    B0 = A0; B1 = A1; B2 = A2;                                       \
    W0 = U0; W1 = U1; W2 = U2;                                       \
    A0 = n0; A1 = n1; A2 = n2; A3 = n3;                              \
    U0 = q0; U1 = q1; U2 = q2; U3 = q3;                              \
    df -= 1.f;                                                       \
}

__global__ __launch_bounds__(64) void dilate_fused(
    const float* __restrict__ y_pred,
    const float* __restrict__ y_true,
    float* __restrict__ out)
{
    const int b = blockIdx.x;
    const int lane = threadIdx.x;

    __shared__ float o_pad[1024];            // [0,256): 0 | [256,512): o | rest 0
    const float4 z4 = make_float4(0.f, 0.f, 0.f, 0.f);
    ((float4*)o_pad)[lane]       = z4;
    ((float4*)o_pad)[lane + 128] = z4;
    ((float4*)o_pad)[lane + 192] = z4;
    ((float4*)o_pad)[lane + 64]  = ((const float4*)(y_pred + b * NN))[lane];
    const float4 tv = ((const float4*)(y_true + b * NN))[lane];
    __syncthreads();

    const float T0 = tv.x, T1 = tv.y, T2 = tv.z, T3 = tv.w;
    const float bigs = BIGS;

    float A0 = BIGS, A1 = BIGS, A2 = BIGS, A3 = BIGS;
    float B0 = BIGS, B1 = BIGS, B2 = BIGS;
    float U0 = 0.f, U1 = 0.f, U2 = 0.f, U3 = 0.f;
    float W0 = 0.f, W1 = 0.f, W2 = 0.f;
    float psA = (lane == 0) ? 0.f : BIGS;    // V[0,0] = 0 corner seed
    float psU = 0.f;
    float w0 = 0.f, w1 = 0.f, w2 = 0.f, w3 = 0.f;

    float df = (float)(8 * lane);            // (i_0 - j_0) at k = 2

    // cell r=0 of step k reads o_pad[PAD + k - 4*lane - 2]; 16B-aligned chunks
    const float* oin = o_pad + (PAD - 4 * lane);
    float4 nxt = *(const float4*)oin;        // o for k = 2..5
    oin += 4;

    #pragma unroll 1
    for (int it = 0; it < 127; ++it) {       // k = 2 .. 509
        const float4 cur = nxt;
        nxt = *(const float4*)oin;           // prefetch next 4-step chunk
        oin += 4;
        DSTEP(cur.x)
        DSTEP(cur.y)
        DSTEP(cur.z)
        DSTEP(cur.w)
    }
    // peeled k = 510, 511, 512 (no step may run after lane63/r3's k=512 write)
    DSTEP(nxt.x)
    DSTEP(nxt.y)
    DSTEP(nxt.z)

    if (lane == 63) {                        // cell (256,256): r=3 of lane 63
        float loss = 0.5f * (A3 * RCSC) * (1.0f / BATCH)
                   + 0.5f * U3 * (1.0f / ((float)BATCH * (float)(NN * NN)));
        atomicAdd(out, loss);
    }
}

extern "C" void kernel_launch(void* const* d_in, const int* in_sizes, int n_in,
                              void* d_out, int out_size, void* d_ws, size_t ws_size,
                              hipStream_t stream)
{
    const float* y_pred = (const float*)d_in[0];   // [64,256,1] -> o (columns)
    const float* y_true = (const float*)d_in[1];   // [64,256,1] -> t (rows)
    hipMemsetAsync(d_out, 0, sizeof(float), stream);
    dilate_fused<<<BATCH, 64, 0, stream>>>(y_pred, y_true, (float*)d_out);
}

// Round 5
// 99.454 us; speedup vs baseline: 3.5160x; 1.4883x over previous
//
#include <hip/hip_runtime.h>

#define BATCH 64
#define NN 256
// Scaled DP domain: V' = V * CSC, CSC = (1/gamma)*log2(e), gamma = 0.01.
#define CSC   144.26950408889634f
#define RCSC  0.0069314718055994531f   // 1/CSC = gamma*ln(2)
#define BIGS  1.4426950408889634e10f   // 1e8 * CSC (scaled boundary)

// 4 waves per batch, 1 DP row per lane: wave w, lane l owns row i = 64w+l+1.
// Skewed wavefront: at global iter n, wave w computes diag k = n + 2 - 8w.
// Intra-wave row handoff: DPP wave_shr1 (lane 0 receives the cross-wave
// boundary value via the DPP `old` operand). Cross-wave handoff: lane 63
// publishes (V',tangent) to a 16-slot LDS ring; consumer (wave w+1) needs the
// value 9 iters after it was written, reads it with a 2-iter prefetch, and a
// barrier every 4 iters orders write->read (write t-9 vs read-issue t-2 always
// straddles >=1 barrier; 16 slots make overwrite races impossible).
// o operand also flows down-lane by DPP; lane 0 injects o[n - 72w] each iter
// from broadcast-prefetched float4s. BIG self-propagation (round-4-validated)
// makes all skew startup/tail cells harmless; ring pre-init = (BIGS, 0).
// Temporal term = JVP tangent of V[N,N] with seed omega[i,j] = (i-j)^2.

__device__ __forceinline__ float shr1(float x, float old) {
    return __int_as_float(__builtin_amdgcn_update_dpp(
        __float_as_int(old), __float_as_int(x), 0x138, 0xF, 0xF, false));
}

#define ITER(J, OINJ) {                                              \
    float sA = shr1(A, rdcA);                                        \
    float sU = shr1(U, rdcU);                                        \
    oc = shr1(oc, OINJ);                                             \
    rdcA = rdnA; rdcU = rdnU;                                        \
    float2 rr = ringr[((J) + 9) & 15];   /* for iter n+2 */          \
    rdnA = rr.x; rdnU = rr.y;                                        \
    float m  = fminf(fminf(A, psA), sA);                             \
    float el = __builtin_amdgcn_exp2f(m - A);                        \
    float ed = __builtin_amdgcn_exp2f(m - psA);                      \
    float eu = __builtin_amdgcn_exp2f(m - sA);                       \
    float s  = el + ed + eu;                                         \
    float x  = T - oc;                                               \
    float nv = fmaf(CSC * x, x, m - __builtin_amdgcn_logf(s));       \
    float num = fmaf(el, U, fmaf(ed, psU, eu * sU));                 \
    float nt  = fmaf(num, __builtin_amdgcn_rcpf(s), dr * dr);        \
    if (l63) ringw[(J)] = make_float2(nv, nt);                       \
    psA = sA; psU = sU; A = nv; U = nt; dr -= 1.0f;                  \
}

__global__ __launch_bounds__(256) void dilate_fused(
    const float* __restrict__ y_pred,
    const float* __restrict__ y_true,
    float* __restrict__ out)
{
    const int b   = blockIdx.x;
    const int tid = threadIdx.x;
    const int w   = tid >> 6;
    const int l   = tid & 63;
    const bool l63 = (l == 63);

    __shared__ float  o_lds[1088];   // zeros | o at [512,768) | zeros
    __shared__ float2 ring[5][16];   // [row w (4 = const BIGS row for wave 0)][slot]

    const float4 z4 = make_float4(0.f, 0.f, 0.f, 0.f);
    if (tid < 128) ((float4*)o_lds)[tid] = z4;                       // [0,512)
    if (tid >= 128 && tid < 208) ((float4*)o_lds)[tid + 64] = z4;    // [768,1088)
    if (tid < 64) ((float4*)(o_lds + 512))[tid] =
        ((const float4*)(y_pred + b * NN))[tid];                     // o
    if (tid < 80) ((float2*)ring)[tid] = make_float2(BIGS, 0.f);     // all slots

    const float T = y_true[b * NN + tid];                            // row i = tid+1
    __syncthreads();

    float A = BIGS, U = 0.f;
    float psA = (tid == 0) ? 0.f : BIGS;                             // V[0,0] corner
    float psU = 0.f;
    float oc = 0.f;
    float dr = (float)(2 * tid + 8 * w);                             // (i - j) at n=0
    float rdcA = BIGS, rdcU = 0.f, rdnA = BIGS, rdnU = 0.f;

    float2* ringw = ring[w];
    const float2* ringr = ring[(w == 0) ? 4 : (w - 1)];
    const float4* o4 = ((const float4*)o_lds) + (128 - 18 * w);

    float4 fA = o4[0], fB = o4[1], fC = o4[2], fD = o4[3]; o4 += 4;

    #pragma unroll 1
    for (int blk = 0; blk < 33; ++blk) {                             // n = 0..527
        float4 gA = o4[0], gB = o4[1], gC = o4[2], gD = o4[3]; o4 += 4;
        ITER(0,  fA.x) ITER(1,  fA.y) ITER(2,  fA.z) ITER(3,  fA.w)
        __syncthreads();
        ITER(4,  fB.x) ITER(5,  fB.y) ITER(6,  fB.z) ITER(7,  fB.w)
        __syncthreads();
        ITER(8,  fC.x) ITER(9,  fC.y) ITER(10, fC.z) ITER(11, fC.w)
        __syncthreads();
        ITER(12, fD.x) ITER(13, fD.y) ITER(14, fD.z) ITER(15, fD.w)
        __syncthreads();
        fA = gA; fB = gB; fC = gC; fD = gD;
    }
    // peel n = 528..534 (wave 3 reaches k = 512 at n = 534); no barriers needed:
    // peel writes are never consumed, peel reads target slots 9..15 (disjoint
    // from peel-written slots 0..6) and data written before the last barrier.
    ITER(0, fA.x) ITER(1, fA.y) ITER(2, fA.z) ITER(3, fA.w)
    ITER(4, fB.x) ITER(5, fB.y) ITER(6, fB.z)

    if (tid == 255) {                       // wave 3, lane 63: cell (256,256)
        float loss = 0.5f * (A * RCSC) * (1.0f / BATCH)
                   + 0.5f * U * (1.0f / ((float)BATCH * (float)(NN * NN)));
        atomicAdd(out, loss);
    }
}

extern "C" void kernel_launch(void* const* d_in, const int* in_sizes, int n_in,
                              void* d_out, int out_size, void* d_ws, size_t ws_size,
                              hipStream_t stream)
{
    const float* y_pred = (const float*)d_in[0];   // [64,256,1] -> o (columns)
    const float* y_true = (const float*)d_in[1];   // [64,256,1] -> t (rows)
    hipMemsetAsync(d_out, 0, sizeof(float), stream);
    dilate_fused<<<BATCH, 256, 0, stream>>>(y_pred, y_true, (float*)d_out);
}